// Round 7
// baseline (285.119 us; speedup 1.0000x reference)
//
#include <hip/hip_runtime.h>
#include <cstdint>

typedef unsigned short u16;
typedef unsigned int u32;

typedef short bf16x8 __attribute__((ext_vector_type(8)));
typedef float f32x4 __attribute__((ext_vector_type(4)));

#define LN2 0.69314718055994530942f
#define LOG2E 1.44269504088896340736f
#define INFF __builtin_inff()

__device__ __forceinline__ u16 f2bf(float f) {
  u32 u = __float_as_uint(f);
  u = (u + 0x7fffu + ((u >> 16) & 1u)) >> 16;
  return (u16)u;
}
__device__ __forceinline__ u32 pack2bf(float a, float b) {
  u32 ta = __float_as_uint(a) + 0x8000u;
  u32 tb = __float_as_uint(b) + 0x8000u;
  return __builtin_amdgcn_perm(tb, ta, 0x07060302u);
}

#if __has_builtin(__builtin_amdgcn_global_load_lds)
#define HAVE_GLDS 1
__device__ __forceinline__ void glds16(const u16* g, u16* l) {
  __builtin_amdgcn_global_load_lds((const __attribute__((address_space(1))) void*)g,
                                   (__attribute__((address_space(3))) void*)l, 16, 0, 0);
}
#else
#define HAVE_GLDS 0
#endif

// ---------------- prep kernels ----------------

__global__ void k_convert_x(const float* __restrict__ in, u16* __restrict__ out, int n4) {
  int i = blockIdx.x * blockDim.x + threadIdx.x;
  if (i < n4) {
    float4 v = ((const float4*)in)[i];
    ushort4 o;
    o.x = f2bf(v.x); o.y = f2bf(v.y); o.z = f2bf(v.z); o.w = f2bf(v.w);
    ((ushort4*)out)[i] = o;
  }
}

__global__ void k_transpose_bf(const float* __restrict__ in, u16* __restrict__ out, int R, int C) {
  __shared__ float t[32][33];
  int c0 = blockIdx.x * 32, r0 = blockIdx.y * 32;
  int tx = threadIdx.x, ty = threadIdx.y;
#pragma unroll
  for (int k = 0; k < 4; k++) t[ty + 8 * k][tx] = in[(size_t)(r0 + ty + 8 * k) * C + c0 + tx];
  __syncthreads();
#pragma unroll
  for (int k = 0; k < 4; k++) out[(size_t)(c0 + ty + 8 * k) * R + r0 + tx] = f2bf(t[tx][ty + 8 * k]);
}

__global__ void k_tables(const float* __restrict__ cP, const float* __restrict__ lP,
                         float* __restrict__ ig2, float* __restrict__ rl) {
  int t = blockIdx.x * blockDim.x + threadIdx.x;
  float c = fabsf(cP[0]);
  if (t < 2048) {
    float lm = lP[0];
    float thr = fabsf(lm * 512.0f);
    float pn = fmaxf((float)t, thr);
    float den = logf(c * pn + 1.0f) + 1e-6f;
    ig2[t] = LN2 / den;
  }
  if (t < 2112) {
    int d = t - 63;
    if (d < 0) d = 0;
    rl[t] = log2f(c * (float)d + 1.0f);
  }
}

__global__ void k_segments(const float* __restrict__ w1, const float* __restrict__ b1,
                           const float* __restrict__ w2, const float* __restrict__ b2,
                           float* __restrict__ segX, float* __restrict__ segA,
                           float* __restrict__ segB, int* __restrict__ segU) {
  __shared__ float xs[32];
  __shared__ float srt[32];
  __shared__ float uniq[32];
  __shared__ int uCnt;
  int t = threadIdx.x;
  if (t < 32) {
    float w = w1[t], b = b1[t];
    xs[t] = (w != 0.0f) ? (-b / w) : INFF;
  }
  __syncthreads();
  if (t < 32) {
    float x = xs[t];
    int r = 0;
    for (int v = 0; v < 32; v++) {
      float xv = xs[v];
      if (xv < x || (xv == x && v < t)) r++;
    }
    srt[r] = x;
  }
  __syncthreads();
  if (t == 0) {
    int u = 0;
    for (int i = 0; i < 32; i++) {
      float v = srt[i];
      if (v < 3.0e38f && (u == 0 || v != uniq[u - 1])) uniq[u++] = v;
    }
    uCnt = u;
    segU[0] = u;
  }
  __syncthreads();
  int u = uCnt;
  if (t < u) segX[t] = uniq[t];
  for (int idx = t; idx < (u + 1) * 16; idx += blockDim.x) {
    int j = idx >> 4, h = idx & 15;
    float p;
    if (u == 0) p = 0.0f;
    else if (j == 0) p = uniq[0] - 1.0f;
    else if (j == u) p = uniq[u - 1] + 1.0f;
    else p = 0.5f * (uniq[j - 1] + uniq[j]);
    float A = b2[h], B = 0.0f;
    for (int w = 0; w < 32; w++) {
      float w1w = w1[w], b1w = b1[w], w2wh = w2[w * 16 + h];
      if (w1w != 0.0f) {
        if (fmaf(w1w, p, b1w) > 0.0f) { B += w1w * w2wh; A += b1w * w2wh; }
      } else if (b1w > 0.0f) {
        A += b1w * w2wh;
      }
    }
    segA[j * 16 + h] = A;
    segB[j * 16 + h] = B;
  }
}

// ---------------- GEMM:  C(MxN) = A(MxK) @ BT(NxK)^T ----------------
// BM=128 fixed, BN in {64,128}. BN=64 -> 2x blocks for small-N (proj).
template <int MODE, int BN>
__launch_bounds__(256, (BN == 64) ? 4 : 3)
__global__ void k_gemm(const u16* __restrict__ A, const u16* __restrict__ BT,
                       const float* __restrict__ bias, float* __restrict__ outF,
                       u16* __restrict__ outQ, u16* __restrict__ outK, u16* __restrict__ outV,
                       int M, int N, int K) {
  constexpr int NT = BN / 32;   // n-subtiles per wave (wave-col covers BN/2)
  constexpr int NCH = BN / 32;  // B staging chunks of 32 rows
  __shared__ u16 As[128 * 64];
  __shared__ u16 Bs[BN * 64];
  const int tid = threadIdx.x;
  const int lane = tid & 63, wave = tid >> 6;
  const int li = lane & 15, quad = lane >> 4;
  const int wrow = (wave >> 1) * 64, wcol = (wave & 1) * (BN / 2);
  const int rb = blockIdx.y * 128, cb = blockIdx.x * BN;

  f32x4 acc[4][NT];
#pragma unroll
  for (int i = 0; i < 4; i++)
#pragma unroll
    for (int j = 0; j < NT; j++) acc[i][j] = (f32x4){0.f, 0.f, 0.f, 0.f};

#if HAVE_GLDS
  const u16* gA = A + (size_t)(rb + (tid >> 3)) * K + (tid & 7) * 8;
  const u16* gB = BT + (size_t)(cb + (tid >> 3)) * K + (tid & 7) * 8;
  u16* lA = As + wave * 512;
  u16* lB = Bs + wave * 512;

  for (int k0 = 0; k0 < K; k0 += 64) {
    __syncthreads();
#pragma unroll
    for (int ch = 0; ch < 4; ch++) glds16(gA + (size_t)ch * 32 * K + k0, lA + ch * 2048);
#pragma unroll
    for (int ch = 0; ch < NCH; ch++) glds16(gB + (size_t)ch * 32 * K + k0, lB + ch * 2048);
    __syncthreads();
#pragma unroll
    for (int c = 0; c < 2; c++) {
      bf16x8 af[4], bfr[NT];
#pragma unroll
      for (int mt = 0; mt < 4; mt++)
        af[mt] = *(const bf16x8*)(&As[(wrow + mt * 16 + li) * 64 + c * 32 + quad * 8]);
#pragma unroll
      for (int nt = 0; nt < NT; nt++)
        bfr[nt] = *(const bf16x8*)(&Bs[(wcol + nt * 16 + li) * 64 + c * 32 + quad * 8]);
#pragma unroll
      for (int mt = 0; mt < 4; mt++)
#pragma unroll
        for (int nt = 0; nt < NT; nt++)
          acc[mt][nt] = __builtin_amdgcn_mfma_f32_16x16x32_bf16(af[mt], bfr[nt], acc[mt][nt], 0, 0, 0);
    }
  }
#else
  for (int k0 = 0; k0 < K; k0 += 64) {
    __syncthreads();
    for (int idx = tid * 8; idx < 128 * 64; idx += 256 * 8) {
      int rr = idx >> 6, cc = idx & 63;
      *(uint4*)(&As[idx]) = *(const uint4*)(A + (size_t)(rb + rr) * K + k0 + cc);
    }
    for (int idx = tid * 8; idx < BN * 64; idx += 256 * 8) {
      int rr = idx >> 6, cc = idx & 63;
      *(uint4*)(&Bs[idx]) = *(const uint4*)(BT + (size_t)(cb + rr) * K + k0 + cc);
    }
    __syncthreads();
#pragma unroll
    for (int c = 0; c < 2; c++) {
      bf16x8 af[4], bfr[NT];
#pragma unroll
      for (int mt = 0; mt < 4; mt++)
        af[mt] = *(const bf16x8*)(&As[(wrow + mt * 16 + li) * 64 + c * 32 + quad * 8]);
#pragma unroll
      for (int nt = 0; nt < NT; nt++)
        bfr[nt] = *(const bf16x8*)(&Bs[(wcol + nt * 16 + li) * 64 + c * 32 + quad * 8]);
#pragma unroll
      for (int mt = 0; mt < 4; mt++)
#pragma unroll
        for (int nt = 0; nt < NT; nt++)
          acc[mt][nt] = __builtin_amdgcn_mfma_f32_16x16x32_bf16(af[mt], bfr[nt], acc[mt][nt], 0, 0, 0);
    }
  }
#endif

#pragma unroll
  for (int mt = 0; mt < 4; mt++)
#pragma unroll
    for (int nt = 0; nt < NT; nt++)
#pragma unroll
      for (int r = 0; r < 4; r++) {
        int row = rb + wrow + mt * 16 + quad * 4 + r;
        int col = cb + wcol + nt * 16 + li;
        float v = acc[mt][nt][r] + bias[col];
        if (MODE == 0) {
          int b = row >> 11, tt = row & 2047;
          int sel = col >> 10, w = col & 1023, h = w >> 6, dd = w & 63;
          u16* dst = (sel == 0) ? outQ : ((sel == 1) ? outK : outV);
          dst[(size_t)((b * 16 + h) * 2048 + tt) * 64 + dd] = f2bf(v);
        } else {
          outF[(size_t)row * N + col] = v;
        }
      }
}

// ---------------- flash attention, S^T formulation, paired q-tiles ----------------
// Single-buffered K/V with 2 barriers per k-tile: LDS ~36.5KB -> 4 blocks/CU.
// Register prefetch of tile kt+1 issued right after the 2nd barrier overlaps
// global latency with the full compute section.
__launch_bounds__(256, 4)
__global__ void k_attn(const u16* __restrict__ Q, const u16* __restrict__ K,
                       const u16* __restrict__ V, u16* __restrict__ Y,
                       const float* __restrict__ ig2, const float* __restrict__ RL,
                       const float* __restrict__ segX, const float* __restrict__ segA,
                       const float* __restrict__ segB, const int* __restrict__ segU) {
  __shared__ u16 Ks[64][72];
  __shared__ u16 Vts[64][72];  // transposed: Vts[d][kk]
  __shared__ u16 Ps[64][72];   // Ps[q][s] (wave-private rows)
  __shared__ float rls[2112];
  __shared__ float sXl[32];
  __shared__ float sAl[33];
  __shared__ float sBl[33];

  const int pr = blockIdx.x, h = blockIdx.y, b = blockIdx.z;
  const int tid = threadIdx.x, lane = tid & 63, wave = tid >> 6;
  const int li = lane & 15, quad = lane >> 4;
  const int bh = b * 16 + h;
  const u16* Qg = Q + (size_t)bh * 2048 * 64;
  const u16* Kg = K + (size_t)bh * 2048 * 64;
  const u16* Vg = V + (size_t)bh * 2048 * 64;

  for (int i = tid; i < 2112; i += 256) rls[i] = RL[i];

  const int u = segU[0];
  float x0 = INFF, A0, B0, A1, B1;
  A0 = segA[h]; B0 = segB[h]; A1 = A0; B1 = B0;
  if (u == 1) { x0 = segX[0]; A1 = segA[16 + h]; B1 = segB[16 + h]; }
  if (u > 1) {
    if (tid < u) sXl[tid] = segX[tid];
    if (tid < u + 1) { sAl[tid] = segA[tid * 16 + h]; sBl[tid] = segB[tid * 16 + h]; }
  }
  const float A0e = A0 * LOG2E, A1e = A1 * LOG2E;
  const float SCL = 0.125f * LOG2E;

  auto run_tile = [&](int qt) {
    const int qw = qt * 64 + wave * 16;
    const int t = qw + li;  // this lane's q-row
    bf16x8 qf[2];
#pragma unroll
    for (int c = 0; c < 2; c++)
      qf[c] = *(const bf16x8*)(Qg + (size_t)t * 64 + c * 32 + quad * 8);

    const float gI = ig2[t];
    const float x0r = x0 / gI;
    const float B0g = B0 * gI * LOG2E, B1g = B1 * gI * LOG2E;
    float mrow = -INFF, lrow = 0.0f;
    f32x4 oacc[4];
#pragma unroll
    for (int nt = 0; nt < 4; nt++) oacc[nt] = (f32x4){0.f, 0.f, 0.f, 0.f};

    // prefetch kt = 0 into registers
    uint4 kv0, kv1, w0, w1;
    {
      const u16* ksrc = Kg + (size_t)(tid >> 2) * 64 + (tid & 3) * 16;
      kv0 = *(const uint4*)(ksrc);
      kv1 = *(const uint4*)(ksrc + 8);
      const u16* vsrc = Vg + (size_t)(2 * (tid & 31)) * 64 + (tid >> 5) * 8;
      w0 = *(const uint4*)(vsrc);
      w1 = *(const uint4*)(vsrc + 64);
    }

    for (int kt = 0; kt <= qt; kt++) {
      const int kb = kt * 64;
      __syncthreads();  // previous iteration's (or tile's/table) LDS readers done
      *(uint4*)(&Ks[tid >> 2][(tid & 3) * 16]) = kv0;
      *(uint4*)(&Ks[tid >> 2][(tid & 3) * 16 + 8]) = kv1;
      {
        const int kkp = tid & 31, d0 = (tid >> 5) * 8;
        const u16* pw0 = (const u16*)&w0;
        const u16* pw1 = (const u16*)&w1;
#pragma unroll
        for (int j = 0; j < 8; j++)
          *(u32*)(&Vts[d0 + j][2 * kkp]) = (u32)pw0[j] | ((u32)pw1[j] << 16);
      }
      __syncthreads();
      if (kt < qt) {  // prefetch next tile; in flight through the compute below
        const u16* ksrc = Kg + (size_t)(kb + 64 + (tid >> 2)) * 64 + (tid & 3) * 16;
        kv0 = *(const uint4*)(ksrc);
        kv1 = *(const uint4*)(ksrc + 8);
        const u16* vsrc = Vg + (size_t)(kb + 64 + 2 * (tid & 31)) * 64 + (tid >> 5) * 8;
        w0 = *(const uint4*)(vsrc);
        w1 = *(const uint4*)(vsrc + 64);
      }

      // S^T = K Q^T : sacc[nt] row s = nt*16+quad*4+r, col q = li
      f32x4 sacc[4];
#pragma unroll
      for (int nt = 0; nt < 4; nt++) sacc[nt] = (f32x4){0.f, 0.f, 0.f, 0.f};
#pragma unroll
      for (int c = 0; c < 2; c++)
#pragma unroll
        for (int nt = 0; nt < 4; nt++) {
          bf16x8 kf = *(const bf16x8*)(&Ks[nt * 16 + li][c * 32 + quad * 8]);
          sacc[nt] = __builtin_amdgcn_mfma_f32_16x16x32_bf16(kf, qf[c], sacc[nt], 0, 0, 0);
        }

      // bias via rl table (LDS)
      const int Cbase = t - kb - quad * 4 + 63;  // in [51, 2110]
      const float* rp = &rls[Cbase - 51];
      if (u <= 1) {
        const int lim = Cbase - 63;
#pragma unroll
        for (int nt = 0; nt < 4; nt++)
#pragma unroll
          for (int r = 0; r < 4; r++) {
            float rlv = rp[51 - nt * 16 - r];
            bool hi = rlv > x0r;
            float z = fmaf(rlv, hi ? B1g : B0g, hi ? A1e : A0e);
            z = fmaf(sacc[nt][r], SCL, z);
            if (kt == qt) z = (nt * 16 + r > lim) ? -INFF : z;
            sacc[nt][r] = z;
          }
      } else {
        const int lim = Cbase - 63;
#pragma unroll
        for (int nt = 0; nt < 4; nt++)
#pragma unroll
          for (int r = 0; r < 4; r++) {
            float nd = rp[51 - nt * 16 - r] * gI;
            int j = 0;
            for (int i = 0; i < u; i++) j += (nd > sXl[i]) ? 1 : 0;
            float z = (fmaf(nd, sBl[j], sAl[j]) + sacc[nt][r] * 0.125f) * LOG2E;
            if (kt == qt) z = (nt * 16 + r > lim) ? -INFF : z;
            sacc[nt][r] = z;
          }
      }

      // per-lane online softmax (row q = li)
      float vm = -INFF;
#pragma unroll
      for (int nt = 0; nt < 4; nt++)
#pragma unroll
        for (int r = 0; r < 4; r++) vm = fmaxf(vm, sacc[nt][r]);
      vm = fmaxf(vm, __shfl_xor(vm, 16, 64));
      vm = fmaxf(vm, __shfl_xor(vm, 32, 64));
      float mnew = fmaxf(mrow, vm);
      float alpha = __builtin_amdgcn_exp2f(mrow - mnew);
      mrow = mnew;
      float s = 0.0f;
#pragma unroll
      for (int nt = 0; nt < 4; nt++)
#pragma unroll
        for (int r = 0; r < 4; r++) {
          float p = __builtin_amdgcn_exp2f(sacc[nt][r] - mnew);
          sacc[nt][r] = p;
          s += p;
        }
      s += __shfl_xor(s, 16, 64);
      s += __shfl_xor(s, 32, 64);
      lrow = lrow * alpha + s;
#pragma unroll
      for (int nt = 0; nt < 4; nt++)
#pragma unroll
        for (int r = 0; r < 4; r++) oacc[nt][r] *= alpha;

      // P^T -> Ps[q][s]; wave-private rows, b64 writes
      const int prow = wave * 16 + li;
#pragma unroll
      for (int nt = 0; nt < 4; nt++) {
        uint2 pk;
        pk.x = pack2bf(sacc[nt][0], sacc[nt][1]);
        pk.y = pack2bf(sacc[nt][2], sacc[nt][3]);
        *(uint2*)(&Ps[prow][nt * 16 + quad * 4]) = pk;
      }

      // O^T += V^T P^T
#pragma unroll
      for (int c = 0; c < 2; c++) {
        bf16x8 pf = *(const bf16x8*)(&Ps[wave * 16 + li][c * 32 + quad * 8]);
#pragma unroll
        for (int nt = 0; nt < 4; nt++) {
          bf16x8 vf = *(const bf16x8*)(&Vts[nt * 16 + li][c * 32 + quad * 8]);
          oacc[nt] = __builtin_amdgcn_mfma_f32_16x16x32_bf16(vf, pf, oacc[nt], 0, 0, 0);
        }
      }
    }

    // epilogue: O^T element (d = nt*16+quad*4+r, q = li) -> Y[b][t][h*64+d]
    float inv = 1.0f / lrow;
    u16* dst = Y + (size_t)(b * 2048 + t) * 1024 + h * 64 + quad * 4;
#pragma unroll
    for (int nt = 0; nt < 4; nt++) {
      uint2 pk;
      pk.x = pack2bf(oacc[nt][0] * inv, oacc[nt][1] * inv);
      pk.y = pack2bf(oacc[nt][2] * inv, oacc[nt][3] * inv);
      *(uint2*)(dst + nt * 16) = pk;
    }
  };

  run_tile(pr);
  run_tile(31 - pr);
}

// ---------------- launcher ----------------
extern "C" void kernel_launch(void* const* d_in, const int* in_sizes, int n_in,
                              void* d_out, int out_size, void* d_ws, size_t ws_size,
                              hipStream_t stream) {
  (void)in_sizes; (void)n_in; (void)out_size; (void)ws_size;
  const float* x = (const float*)d_in[0];
  const float* Wqkv = (const float*)d_in[1];
  const float* bqkv = (const float*)d_in[2];
  const float* Wproj = (const float*)d_in[3];
  const float* bproj = (const float*)d_in[4];
  const float* w1 = (const float*)d_in[5];
  const float* b1 = (const float*)d_in[6];
  const float* w2 = (const float*)d_in[7];
  const float* b2 = (const float*)d_in[8];
  const float* cP = (const float*)d_in[9];
  const float* lP = (const float*)d_in[10];

  char* ws = (char*)d_ws;
  u16* Xbf = (u16*)(ws);                          // 8 MB
  u16* WqkvT = (u16*)(ws + (size_t)(8 << 20));    // 6 MB
  u16* WprojT = (u16*)(ws + (size_t)(14 << 20));  // 2 MB
  u16* Qb = (u16*)(ws + (size_t)(16 << 20));      // 8 MB
  u16* Kb = (u16*)(ws + (size_t)(24 << 20));      // 8 MB
  u16* Vb = (u16*)(ws + (size_t)(32 << 20));      // 8 MB
  u16* Yb = (u16*)(ws + (size_t)(40 << 20));      // 8 MB
  float* IG = (float*)(ws + (size_t)(48 << 20));  // tables
  float* RL = IG + 2048;
  float* SEGX = RL + 2112;
  float* SEGA = SEGX + 32;
  float* SEGB = SEGA + 33 * 16;
  int* SEGU = (int*)(SEGB + 33 * 16);

  k_convert_x<<<4096, 256, 0, stream>>>(x, Xbf, 1048576);
  k_transpose_bf<<<dim3(96, 32), dim3(32, 8), 0, stream>>>(Wqkv, WqkvT, 1024, 3072);
  k_transpose_bf<<<dim3(32, 32), dim3(32, 8), 0, stream>>>(Wproj, WprojT, 1024, 1024);
  k_tables<<<9, 256, 0, stream>>>(cP, lP, IG, RL);
  k_segments<<<1, 64, 0, stream>>>(w1, b1, w2, b2, SEGX, SEGA, SEGB, SEGU);

  k_gemm<0, 128><<<dim3(24, 32), 256, 0, stream>>>(Xbf, WqkvT, bqkv, nullptr, Qb, Kb, Vb,
                                                   4096, 3072, 1024);
  k_attn<<<dim3(16, 16, 2), 256, 0, stream>>>(Qb, Kb, Vb, Yb, IG, RL, SEGX, SEGA, SEGB, SEGU);
  k_gemm<1, 64><<<dim3(16, 32), 256, 0, stream>>>(Yb, WprojT, bproj, (float*)d_out, nullptr,
                                                  nullptr, nullptr, 4096, 1024, 1024);
}

// Round 8
// 235.941 us; speedup vs baseline: 1.2084x; 1.2084x over previous
//
#include <hip/hip_runtime.h>
#include <cstdint>

typedef unsigned short u16;
typedef unsigned int u32;

typedef short bf16x8 __attribute__((ext_vector_type(8)));
typedef float f32x4 __attribute__((ext_vector_type(4)));

#define LN2 0.69314718055994530942f
#define LOG2E 1.44269504088896340736f
#define INFF __builtin_inff()

__device__ __forceinline__ u16 f2bf(float f) {
  u32 u = __float_as_uint(f);
  u = (u + 0x7fffu + ((u >> 16) & 1u)) >> 16;
  return (u16)u;
}
__device__ __forceinline__ u32 pack2bf(float a, float b) {
  u32 ta = __float_as_uint(a) + 0x8000u;
  u32 tb = __float_as_uint(b) + 0x8000u;
  return __builtin_amdgcn_perm(tb, ta, 0x07060302u);
}

#if __has_builtin(__builtin_amdgcn_global_load_lds)
#define HAVE_GLDS 1
__device__ __forceinline__ void glds16(const u16* g, u16* l) {
  __builtin_amdgcn_global_load_lds((const __attribute__((address_space(1))) void*)g,
                                   (__attribute__((address_space(3))) void*)l, 16, 0, 0);
}
#else
#define HAVE_GLDS 0
#endif

// ---------------- prep kernels ----------------

__global__ void k_convert_x(const float* __restrict__ in, u16* __restrict__ out, int n4) {
  int i = blockIdx.x * blockDim.x + threadIdx.x;
  if (i < n4) {
    float4 v = ((const float4*)in)[i];
    ushort4 o;
    o.x = f2bf(v.x); o.y = f2bf(v.y); o.z = f2bf(v.z); o.w = f2bf(v.w);
    ((ushort4*)out)[i] = o;
  }
}

__global__ void k_transpose_bf(const float* __restrict__ in, u16* __restrict__ out, int R, int C) {
  __shared__ float t[32][33];
  int c0 = blockIdx.x * 32, r0 = blockIdx.y * 32;
  int tx = threadIdx.x, ty = threadIdx.y;
#pragma unroll
  for (int k = 0; k < 4; k++) t[ty + 8 * k][tx] = in[(size_t)(r0 + ty + 8 * k) * C + c0 + tx];
  __syncthreads();
#pragma unroll
  for (int k = 0; k < 4; k++) out[(size_t)(c0 + ty + 8 * k) * R + r0 + tx] = f2bf(t[tx][ty + 8 * k]);
}

__global__ void k_tables(const float* __restrict__ cP, const float* __restrict__ lP,
                         float* __restrict__ ig2, float* __restrict__ rl) {
  int t = blockIdx.x * blockDim.x + threadIdx.x;
  float c = fabsf(cP[0]);
  if (t < 2048) {
    float lm = lP[0];
    float thr = fabsf(lm * 512.0f);
    float pn = fmaxf((float)t, thr);
    float den = logf(c * pn + 1.0f) + 1e-6f;
    ig2[t] = LN2 / den;
  }
  if (t < 2112) {
    int d = t - 63;
    if (d < 0) d = 0;
    rl[t] = log2f(c * (float)d + 1.0f);
  }
}

__global__ void k_segments(const float* __restrict__ w1, const float* __restrict__ b1,
                           const float* __restrict__ w2, const float* __restrict__ b2,
                           float* __restrict__ segX, float* __restrict__ segA,
                           float* __restrict__ segB, int* __restrict__ segU) {
  __shared__ float xs[32];
  __shared__ float srt[32];
  __shared__ float uniq[32];
  __shared__ int uCnt;
  int t = threadIdx.x;
  if (t < 32) {
    float w = w1[t], b = b1[t];
    xs[t] = (w != 0.0f) ? (-b / w) : INFF;
  }
  __syncthreads();
  if (t < 32) {
    float x = xs[t];
    int r = 0;
    for (int v = 0; v < 32; v++) {
      float xv = xs[v];
      if (xv < x || (xv == x && v < t)) r++;
    }
    srt[r] = x;
  }
  __syncthreads();
  if (t == 0) {
    int u = 0;
    for (int i = 0; i < 32; i++) {
      float v = srt[i];
      if (v < 3.0e38f && (u == 0 || v != uniq[u - 1])) uniq[u++] = v;
    }
    uCnt = u;
    segU[0] = u;
  }
  __syncthreads();
  int u = uCnt;
  if (t < u) segX[t] = uniq[t];
  for (int idx = t; idx < (u + 1) * 16; idx += blockDim.x) {
    int j = idx >> 4, h = idx & 15;
    float p;
    if (u == 0) p = 0.0f;
    else if (j == 0) p = uniq[0] - 1.0f;
    else if (j == u) p = uniq[u - 1] + 1.0f;
    else p = 0.5f * (uniq[j - 1] + uniq[j]);
    float A = b2[h], B = 0.0f;
    for (int w = 0; w < 32; w++) {
      float w1w = w1[w], b1w = b1[w], w2wh = w2[w * 16 + h];
      if (w1w != 0.0f) {
        if (fmaf(w1w, p, b1w) > 0.0f) { B += w1w * w2wh; A += b1w * w2wh; }
      } else if (b1w > 0.0f) {
        A += b1w * w2wh;
      }
    }
    segA[j * 16 + h] = A;
    segB[j * 16 + h] = B;
  }
}

// ---------------- GEMM:  C(MxN) = A(MxK) @ BT(NxK)^T ----------------
template <int MODE, int BN>
__launch_bounds__(256, 3)
__global__ void k_gemm(const u16* __restrict__ A, const u16* __restrict__ BT,
                       const float* __restrict__ bias, float* __restrict__ outF,
                       u16* __restrict__ outQ, u16* __restrict__ outK, u16* __restrict__ outV,
                       int M, int N, int K) {
  constexpr int NT = BN / 32;
  constexpr int NCH = BN / 32;
  __shared__ u16 As[128 * 64];
  __shared__ u16 Bs[BN * 64];
  const int tid = threadIdx.x;
  const int lane = tid & 63, wave = tid >> 6;
  const int li = lane & 15, quad = lane >> 4;
  const int wrow = (wave >> 1) * 64, wcol = (wave & 1) * (BN / 2);
  const int rb = blockIdx.y * 128, cb = blockIdx.x * BN;

  f32x4 acc[4][NT];
#pragma unroll
  for (int i = 0; i < 4; i++)
#pragma unroll
    for (int j = 0; j < NT; j++) acc[i][j] = (f32x4){0.f, 0.f, 0.f, 0.f};

#if HAVE_GLDS
  const u16* gA = A + (size_t)(rb + (tid >> 3)) * K + (tid & 7) * 8;
  const u16* gB = BT + (size_t)(cb + (tid >> 3)) * K + (tid & 7) * 8;
  u16* lA = As + wave * 512;
  u16* lB = Bs + wave * 512;

  for (int k0 = 0; k0 < K; k0 += 64) {
    __syncthreads();
#pragma unroll
    for (int ch = 0; ch < 4; ch++) glds16(gA + (size_t)ch * 32 * K + k0, lA + ch * 2048);
#pragma unroll
    for (int ch = 0; ch < NCH; ch++) glds16(gB + (size_t)ch * 32 * K + k0, lB + ch * 2048);
    __syncthreads();
#pragma unroll
    for (int c = 0; c < 2; c++) {
      bf16x8 af[4], bfr[NT];
#pragma unroll
      for (int mt = 0; mt < 4; mt++)
        af[mt] = *(const bf16x8*)(&As[(wrow + mt * 16 + li) * 64 + c * 32 + quad * 8]);
#pragma unroll
      for (int nt = 0; nt < NT; nt++)
        bfr[nt] = *(const bf16x8*)(&Bs[(wcol + nt * 16 + li) * 64 + c * 32 + quad * 8]);
#pragma unroll
      for (int mt = 0; mt < 4; mt++)
#pragma unroll
        for (int nt = 0; nt < NT; nt++)
          acc[mt][nt] = __builtin_amdgcn_mfma_f32_16x16x32_bf16(af[mt], bfr[nt], acc[mt][nt], 0, 0, 0);
    }
  }
#else
  for (int k0 = 0; k0 < K; k0 += 64) {
    __syncthreads();
    for (int idx = tid * 8; idx < 128 * 64; idx += 256 * 8) {
      int rr = idx >> 6, cc = idx & 63;
      *(uint4*)(&As[idx]) = *(const uint4*)(A + (size_t)(rb + rr) * K + k0 + cc);
    }
    for (int idx = tid * 8; idx < BN * 64; idx += 256 * 8) {
      int rr = idx >> 6, cc = idx & 63;
      *(uint4*)(&Bs[idx]) = *(const uint4*)(BT + (size_t)(cb + rr) * K + k0 + cc);
    }
    __syncthreads();
#pragma unroll
    for (int c = 0; c < 2; c++) {
      bf16x8 af[4], bfr[NT];
#pragma unroll
      for (int mt = 0; mt < 4; mt++)
        af[mt] = *(const bf16x8*)(&As[(wrow + mt * 16 + li) * 64 + c * 32 + quad * 8]);
#pragma unroll
      for (int nt = 0; nt < NT; nt++)
        bfr[nt] = *(const bf16x8*)(&Bs[(wcol + nt * 16 + li) * 64 + c * 32 + quad * 8]);
#pragma unroll
      for (int mt = 0; mt < 4; mt++)
#pragma unroll
        for (int nt = 0; nt < NT; nt++)
          acc[mt][nt] = __builtin_amdgcn_mfma_f32_16x16x32_bf16(af[mt], bfr[nt], acc[mt][nt], 0, 0, 0);
    }
  }
#endif

#pragma unroll
  for (int mt = 0; mt < 4; mt++)
#pragma unroll
    for (int nt = 0; nt < NT; nt++)
#pragma unroll
      for (int r = 0; r < 4; r++) {
        int row = rb + wrow + mt * 16 + quad * 4 + r;
        int col = cb + wcol + nt * 16 + li;
        float v = acc[mt][nt][r] + bias[col];
        if (MODE == 0) {
          int b = row >> 11, tt = row & 2047;
          int sel = col >> 10, w = col & 1023, h = w >> 6, dd = w & 63;
          u16* dst = (sel == 0) ? outQ : ((sel == 1) ? outK : outV);
          dst[(size_t)((b * 16 + h) * 2048 + tt) * 64 + dd] = f2bf(v);
        } else {
          outF[(size_t)row * N + col] = v;
        }
      }
}

// ---------------- flash attention, S^T formulation, paired q-tiles ----------------
// Single-buffered K/V (36.9KB LDS -> 4 blocks/CU capacity), register prefetch of
// tile kt+1 across the compute section. launch_bounds(256,3): VGPR budget ~170
// so no scratch spill (the (256,4) variant spilled: 64 VGPR, WRITE_SIZE 8->67MB).
__launch_bounds__(256, 3)
__global__ void k_attn(const u16* __restrict__ Q, const u16* __restrict__ K,
                       const u16* __restrict__ V, u16* __restrict__ Y,
                       const float* __restrict__ ig2, const float* __restrict__ RL,
                       const float* __restrict__ segX, const float* __restrict__ segA,
                       const float* __restrict__ segB, const int* __restrict__ segU) {
  __shared__ u16 Ks[64][72];
  __shared__ u16 Vts[64][72];  // transposed: Vts[d][kk]
  __shared__ u16 Ps[64][72];   // Ps[q][s] (wave-private rows)
  __shared__ float rls[2112];
  __shared__ float sXl[32];
  __shared__ float sAl[33];
  __shared__ float sBl[33];

  const int pr = blockIdx.x, h = blockIdx.y, b = blockIdx.z;
  const int tid = threadIdx.x, lane = tid & 63, wave = tid >> 6;
  const int li = lane & 15, quad = lane >> 4;
  const int bh = b * 16 + h;
  const u16* Qg = Q + (size_t)bh * 2048 * 64;
  const u16* Kg = K + (size_t)bh * 2048 * 64;
  const u16* Vg = V + (size_t)bh * 2048 * 64;

  for (int i = tid; i < 2112; i += 256) rls[i] = RL[i];

  const int u = segU[0];
  float x0 = INFF, A0, B0, A1, B1;
  A0 = segA[h]; B0 = segB[h]; A1 = A0; B1 = B0;
  if (u == 1) { x0 = segX[0]; A1 = segA[16 + h]; B1 = segB[16 + h]; }
  if (u > 1) {
    if (tid < u) sXl[tid] = segX[tid];
    if (tid < u + 1) { sAl[tid] = segA[tid * 16 + h]; sBl[tid] = segB[tid * 16 + h]; }
  }
  const float A0e = A0 * LOG2E, A1e = A1 * LOG2E;
  const float SCL = 0.125f * LOG2E;

  auto run_tile = [&](int qt) {
    const int qw = qt * 64 + wave * 16;
    const int t = qw + li;  // this lane's q-row
    bf16x8 qf[2];
#pragma unroll
    for (int c = 0; c < 2; c++)
      qf[c] = *(const bf16x8*)(Qg + (size_t)t * 64 + c * 32 + quad * 8);

    const float gI = ig2[t];
    const float x0r = x0 / gI;
    const float B0g = B0 * gI * LOG2E, B1g = B1 * gI * LOG2E;
    float mrow = -INFF, lrow = 0.0f;
    f32x4 oacc[4];
#pragma unroll
    for (int nt = 0; nt < 4; nt++) oacc[nt] = (f32x4){0.f, 0.f, 0.f, 0.f};

    // prefetch kt = 0 into registers
    uint4 kv0, kv1, w0, w1;
    {
      const u16* ksrc = Kg + (size_t)(tid >> 2) * 64 + (tid & 3) * 16;
      kv0 = *(const uint4*)(ksrc);
      kv1 = *(const uint4*)(ksrc + 8);
      const u16* vsrc = Vg + (size_t)(2 * (tid & 31)) * 64 + (tid >> 5) * 8;
      w0 = *(const uint4*)(vsrc);
      w1 = *(const uint4*)(vsrc + 64);
    }

    for (int kt = 0; kt <= qt; kt++) {
      const int kb = kt * 64;
      __syncthreads();  // previous iteration's LDS readers done
      *(uint4*)(&Ks[tid >> 2][(tid & 3) * 16]) = kv0;
      *(uint4*)(&Ks[tid >> 2][(tid & 3) * 16 + 8]) = kv1;
      {
        const int kkp = tid & 31, d0 = (tid >> 5) * 8;
        const u16* pw0 = (const u16*)&w0;
        const u16* pw1 = (const u16*)&w1;
#pragma unroll
        for (int j = 0; j < 8; j++)
          *(u32*)(&Vts[d0 + j][2 * kkp]) = (u32)pw0[j] | ((u32)pw1[j] << 16);
      }
      __syncthreads();
      if (kt < qt) {  // prefetch next tile; in flight through the compute below
        const u16* ksrc = Kg + (size_t)(kb + 64 + (tid >> 2)) * 64 + (tid & 3) * 16;
        kv0 = *(const uint4*)(ksrc);
        kv1 = *(const uint4*)(ksrc + 8);
        const u16* vsrc = Vg + (size_t)(kb + 64 + 2 * (tid & 31)) * 64 + (tid >> 5) * 8;
        w0 = *(const uint4*)(vsrc);
        w1 = *(const uint4*)(vsrc + 64);
      }

      // S^T = K Q^T : sacc[nt] row s = nt*16+quad*4+r, col q = li
      f32x4 sacc[4];
#pragma unroll
      for (int nt = 0; nt < 4; nt++) sacc[nt] = (f32x4){0.f, 0.f, 0.f, 0.f};
#pragma unroll
      for (int c = 0; c < 2; c++)
#pragma unroll
        for (int nt = 0; nt < 4; nt++) {
          bf16x8 kf = *(const bf16x8*)(&Ks[nt * 16 + li][c * 32 + quad * 8]);
          sacc[nt] = __builtin_amdgcn_mfma_f32_16x16x32_bf16(kf, qf[c], sacc[nt], 0, 0, 0);
        }

      // bias via rl table (LDS)
      const int Cbase = t - kb - quad * 4 + 63;  // in [51, 2110]
      const float* rp = &rls[Cbase - 51];
      if (u <= 1) {
        const int lim = Cbase - 63;
#pragma unroll
        for (int nt = 0; nt < 4; nt++)
#pragma unroll
          for (int r = 0; r < 4; r++) {
            float rlv = rp[51 - nt * 16 - r];
            bool hi = rlv > x0r;
            float z = fmaf(rlv, hi ? B1g : B0g, hi ? A1e : A0e);
            z = fmaf(sacc[nt][r], SCL, z);
            if (kt == qt) z = (nt * 16 + r > lim) ? -INFF : z;
            sacc[nt][r] = z;
          }
      } else {
        const int lim = Cbase - 63;
#pragma unroll
        for (int nt = 0; nt < 4; nt++)
#pragma unroll
          for (int r = 0; r < 4; r++) {
            float nd = rp[51 - nt * 16 - r] * gI;
            int j = 0;
            for (int i = 0; i < u; i++) j += (nd > sXl[i]) ? 1 : 0;
            float z = (fmaf(nd, sBl[j], sAl[j]) + sacc[nt][r] * 0.125f) * LOG2E;
            if (kt == qt) z = (nt * 16 + r > lim) ? -INFF : z;
            sacc[nt][r] = z;
          }
      }

      // per-lane online softmax (row q = li)
      float vm = -INFF;
#pragma unroll
      for (int nt = 0; nt < 4; nt++)
#pragma unroll
        for (int r = 0; r < 4; r++) vm = fmaxf(vm, sacc[nt][r]);
      vm = fmaxf(vm, __shfl_xor(vm, 16, 64));
      vm = fmaxf(vm, __shfl_xor(vm, 32, 64));
      float mnew = fmaxf(mrow, vm);
      float alpha = __builtin_amdgcn_exp2f(mrow - mnew);
      mrow = mnew;
      float s = 0.0f;
#pragma unroll
      for (int nt = 0; nt < 4; nt++)
#pragma unroll
        for (int r = 0; r < 4; r++) {
          float p = __builtin_amdgcn_exp2f(sacc[nt][r] - mnew);
          sacc[nt][r] = p;
          s += p;
        }
      s += __shfl_xor(s, 16, 64);
      s += __shfl_xor(s, 32, 64);
      lrow = lrow * alpha + s;
#pragma unroll
      for (int nt = 0; nt < 4; nt++)
#pragma unroll
        for (int r = 0; r < 4; r++) oacc[nt][r] *= alpha;

      // P^T -> Ps[q][s]; wave-private rows, b64 writes
      const int prow = wave * 16 + li;
#pragma unroll
      for (int nt = 0; nt < 4; nt++) {
        uint2 pk;
        pk.x = pack2bf(sacc[nt][0], sacc[nt][1]);
        pk.y = pack2bf(sacc[nt][2], sacc[nt][3]);
        *(uint2*)(&Ps[prow][nt * 16 + quad * 4]) = pk;
      }

      // O^T += V^T P^T
#pragma unroll
      for (int c = 0; c < 2; c++) {
        bf16x8 pf = *(const bf16x8*)(&Ps[wave * 16 + li][c * 32 + quad * 8]);
#pragma unroll
        for (int nt = 0; nt < 4; nt++) {
          bf16x8 vf = *(const bf16x8*)(&Vts[nt * 16 + li][c * 32 + quad * 8]);
          oacc[nt] = __builtin_amdgcn_mfma_f32_16x16x32_bf16(vf, pf, oacc[nt], 0, 0, 0);
        }
      }
    }

    // epilogue: O^T element (d = nt*16+quad*4+r, q = li) -> Y[b][t][h*64+d]
    float inv = 1.0f / lrow;
    u16* dst = Y + (size_t)(b * 2048 + t) * 1024 + h * 64 + quad * 4;
#pragma unroll
    for (int nt = 0; nt < 4; nt++) {
      uint2 pk;
      pk.x = pack2bf(oacc[nt][0] * inv, oacc[nt][1] * inv);
      pk.y = pack2bf(oacc[nt][2] * inv, oacc[nt][3] * inv);
      *(uint2*)(dst + nt * 16) = pk;
    }
  };

  run_tile(pr);
  run_tile(31 - pr);
}

// ---------------- launcher ----------------
extern "C" void kernel_launch(void* const* d_in, const int* in_sizes, int n_in,
                              void* d_out, int out_size, void* d_ws, size_t ws_size,
                              hipStream_t stream) {
  (void)in_sizes; (void)n_in; (void)out_size; (void)ws_size;
  const float* x = (const float*)d_in[0];
  const float* Wqkv = (const float*)d_in[1];
  const float* bqkv = (const float*)d_in[2];
  const float* Wproj = (const float*)d_in[3];
  const float* bproj = (const float*)d_in[4];
  const float* w1 = (const float*)d_in[5];
  const float* b1 = (const float*)d_in[6];
  const float* w2 = (const float*)d_in[7];
  const float* b2 = (const float*)d_in[8];
  const float* cP = (const float*)d_in[9];
  const float* lP = (const float*)d_in[10];

  char* ws = (char*)d_ws;
  u16* Xbf = (u16*)(ws);                          // 8 MB
  u16* WqkvT = (u16*)(ws + (size_t)(8 << 20));    // 6 MB
  u16* WprojT = (u16*)(ws + (size_t)(14 << 20));  // 2 MB
  u16* Qb = (u16*)(ws + (size_t)(16 << 20));      // 8 MB
  u16* Kb = (u16*)(ws + (size_t)(24 << 20));      // 8 MB
  u16* Vb = (u16*)(ws + (size_t)(32 << 20));      // 8 MB
  u16* Yb = (u16*)(ws + (size_t)(40 << 20));      // 8 MB
  float* IG = (float*)(ws + (size_t)(48 << 20));  // tables
  float* RL = IG + 2048;
  float* SEGX = RL + 2112;
  float* SEGA = SEGX + 32;
  float* SEGB = SEGA + 33 * 16;
  int* SEGU = (int*)(SEGB + 33 * 16);

  k_convert_x<<<4096, 256, 0, stream>>>(x, Xbf, 1048576);
  k_transpose_bf<<<dim3(96, 32), dim3(32, 8), 0, stream>>>(Wqkv, WqkvT, 1024, 3072);
  k_transpose_bf<<<dim3(32, 32), dim3(32, 8), 0, stream>>>(Wproj, WprojT, 1024, 1024);
  k_tables<<<9, 256, 0, stream>>>(cP, lP, IG, RL);
  k_segments<<<1, 64, 0, stream>>>(w1, b1, w2, b2, SEGX, SEGA, SEGB, SEGU);

  k_gemm<0, 128><<<dim3(24, 32), 256, 0, stream>>>(Xbf, WqkvT, bqkv, nullptr, Qb, Kb, Vb,
                                                   4096, 3072, 1024);
  k_attn<<<dim3(16, 16, 2), 256, 0, stream>>>(Qb, Kb, Vb, Yb, IG, RL, SEGX, SEGA, SEGB, SEGU);
  k_gemm<1, 64><<<dim3(16, 32), 256, 0, stream>>>(Yb, WprojT, bproj, (float*)d_out, nullptr,
                                                  nullptr, nullptr, 4096, 1024, 1024);
}